// Round 17
// baseline (137.751 us; speedup 1.0000x reference)
//
#include <hip/hip_runtime.h>
#include <hip/hip_bf16.h>

#define Bb 8
#define Cc 64
#define Tt 16
#define Hh 56
#define Ww 56
#define COUT 128
#define HW (Hh*Ww)            // 3136
#define THW (Tt*HW)           // 50176
#define NPG ((double)(32*THW))

typedef __attribute__((ext_vector_type(8))) short short8v;   // 8 bf16
typedef __attribute__((ext_vector_type(4))) float f32x4;

__device__ __forceinline__ unsigned short f2bf(float x) {
  __hip_bfloat16 h = __float2bfloat16(x);
  return *reinterpret_cast<unsigned short*>(&h);
}
__device__ __forceinline__ unsigned int pack2(float a, float b) {
  return (unsigned int)f2bf(a) | ((unsigned int)f2bf(b) << 16);
}

// ---------------------------------------------------------------------------
// K1: fused depthwise spatial 3x3 + temporal 3-tap. One block per
// (b, channel-PAIR, t-HALF). Raw planes in LDS as FP32 (two channels,
// double-buffered) -> no bf16 pack/unpack in the spatial hot loop
// (~40% of k1's VALU). Temporal accumulation in registers (two rolling
// z-planes); bf16 pack only at z-emit. Block 0 zeroes the stats buffer.
// ---------------------------------------------------------------------------
__global__ __launch_bounds__(256) void k1_dwconv(
    const float* __restrict__ x,  const float* __restrict__ sw,
    const float* __restrict__ sb, const float* __restrict__ tw,
    const float* __restrict__ tb, unsigned int* __restrict__ zq,
    double* __restrict__ stats)
{
  __shared__ float rawA[2][HW];   // 24.5 KB
  __shared__ float rawB[2][HW];   // 24.5 KB

  const int tid = threadIdx.x;
  if (blockIdx.x == 0 && tid < 64) stats[tid] = 0.0;

  const int tq = blockIdx.x & 1;
  const int c2 = (blockIdx.x >> 1) & 31;
  const int b  =  blockIdx.x >> 6;
  const int t0 = tq * 8;
  const int ca = c2 * 2, cb = ca + 1;

  float s9a[9], s9b[9];
#pragma unroll
  for (int k = 0; k < 9; ++k) { s9a[k] = sw[ca * 9 + k]; s9b[k] = sw[cb * 9 + k]; }
  const float tw0a = tw[ca * 3 + 0], tw1a = tw[ca * 3 + 1], tw2a = tw[ca * 3 + 2];
  const float tw0b = tw[cb * 3 + 0], tw1b = tw[cb * 3 + 1], tw2b = tw[cb * 3 + 2];
  const float sba = sb[ca], sbb = sb[cb];
  const float tba = tb[ca], tbb = tb[cb];

  const float* xa = x + (size_t)(b * Cc + ca) * THW;
  const float* xb = x + (size_t)(b * Cc + cb) * THW;
  unsigned int* zbase = zq + (size_t)(b * 32 + c2) * THW;

  float accP[4][8], accC[4][8];
#pragma unroll
  for (int i = 0; i < 4; ++i)
#pragma unroll
    for (int j = 0; j < 8; ++j) { accP[i][j] = 0.f; accC[i][j] = 0.f; }

  for (int k = 0; k < 10; ++k) {
    const int tt = t0 - 1 + k;
    const bool val = (tt >= 0 && tt < Tt);
    float* rwA = rawA[k & 1];
    float* rwB = rawB[k & 1];

    if (val) {
      const float* xpa = xa + tt * HW;
      const float* xpb = xb + tt * HW;
#pragma unroll
      for (int i = 0; i < 4; ++i) {
        int f = tid + i * 256;
        if (f < HW / 4) {
          *(float4*)&rwA[f * 4] = *(const float4*)(xpa + f * 4);
          *(float4*)&rwB[f * 4] = *(const float4*)(xpb + f * 4);
        }
      }
    }
    __syncthreads();   // single barrier per plane (dbuf bounds skew)

    const bool emit = (k >= 2);
    const int t_out = tt - 1;
    unsigned int* zp = zbase + (size_t)t_out * HW;

#pragma unroll
    for (int i = 0; i < 4; ++i) {
      int q = tid + i * 256;
      if (q < HW / 4) {
        float s[8];
        if (val) {
          int h  = q / 14;
          int w0 = (q - h * 14) * 4;
          float sa0 = sba, sa1 = sba, sa2 = sba, sa3 = sba;
          float sb0 = sbb, sb1 = sbb, sb2 = sbb, sb3 = sbb;
#pragma unroll
          for (int dh = -1; dh <= 1; ++dh) {
            int hh = h + dh;
            if (hh < 0 || hh > Hh - 1) continue;
            const float* rA = &rwA[hh * Ww + w0];
            const float* rB = &rwB[hh * Ww + w0];
            float4 mA = *(const float4*)rA;
            float4 mB = *(const float4*)rB;
            float lA = (w0 > 0)      ? rA[-1] : 0.0f;
            float rAh = (w0 < Ww - 4) ? rA[4] : 0.0f;
            float lB = (w0 > 0)      ? rB[-1] : 0.0f;
            float rBh = (w0 < Ww - 4) ? rB[4] : 0.0f;
            float k0a = s9a[(dh + 1) * 3 + 0], k1a = s9a[(dh + 1) * 3 + 1], k2a = s9a[(dh + 1) * 3 + 2];
            float k0b = s9b[(dh + 1) * 3 + 0], k1b = s9b[(dh + 1) * 3 + 1], k2b = s9b[(dh + 1) * 3 + 2];
            sa0 = fmaf(k0a, lA,   fmaf(k1a, mA.x, fmaf(k2a, mA.y, sa0)));
            sa1 = fmaf(k0a, mA.x, fmaf(k1a, mA.y, fmaf(k2a, mA.z, sa1)));
            sa2 = fmaf(k0a, mA.y, fmaf(k1a, mA.z, fmaf(k2a, mA.w, sa2)));
            sa3 = fmaf(k0a, mA.z, fmaf(k1a, mA.w, fmaf(k2a, rAh,  sa3)));
            sb0 = fmaf(k0b, lB,   fmaf(k1b, mB.x, fmaf(k2b, mB.y, sb0)));
            sb1 = fmaf(k0b, mB.x, fmaf(k1b, mB.y, fmaf(k2b, mB.z, sb1)));
            sb2 = fmaf(k0b, mB.y, fmaf(k1b, mB.z, fmaf(k2b, mB.w, sb2)));
            sb3 = fmaf(k0b, mB.z, fmaf(k1b, mB.w, fmaf(k2b, rBh,  sb3)));
          }
          s[0] = sa0; s[1] = sa1; s[2] = sa2; s[3] = sa3;
          s[4] = sb0; s[5] = sb1; s[6] = sb2; s[7] = sb3;
        } else {
#pragma unroll
          for (int j = 0; j < 8; ++j) s[j] = 0.0f;
        }

        if (emit) {
          float z0 = fmaf(tw2a, s[0], accP[i][0]);
          float z1 = fmaf(tw2a, s[1], accP[i][1]);
          float z2 = fmaf(tw2a, s[2], accP[i][2]);
          float z3 = fmaf(tw2a, s[3], accP[i][3]);
          float z4 = fmaf(tw2b, s[4], accP[i][4]);
          float z5 = fmaf(tw2b, s[5], accP[i][5]);
          float z6 = fmaf(tw2b, s[6], accP[i][6]);
          float z7 = fmaf(tw2b, s[7], accP[i][7]);
          uint4 o;
          o.x = pack2(z0, z4);
          o.y = pack2(z1, z5);
          o.z = pack2(z2, z6);
          o.w = pack2(z3, z7);
          *(uint4*)(zp + q * 4) = o;
        }
#pragma unroll
        for (int j = 0; j < 4; ++j) {
          accP[i][j]     = fmaf(tw1a, s[j],     accC[i][j]);
          accP[i][j + 4] = fmaf(tw1b, s[j + 4], accC[i][j + 4]);
          accC[i][j]     = fmaf(tw0a, s[j],     tba);
          accC[i][j + 4] = fmaf(tw0b, s[j + 4], tbb);
        }
      }
    }
    // no trailing barrier: next iteration writes the OTHER raw buffer.
  }
}

// ---------------------------------------------------------------------------
// K2/K3: 128 pos x 128 out tile, 4 waves (wave = GN group), 4 subtiles/block,
// double-buffered TRANSPOSED LDS tile zt[128 pos][36 c2-pad].
// MFMA: A = z (row = pos), B = W (col = o); lane owns o = lane&15,
// reg-quad = 4 consecutive positions.
// ---------------------------------------------------------------------------
#define WFRAG_LOAD()                                                           \
  const int lr = tid & 15, lg = (tid >> 4) & 3, wv = tid >> 6;                 \
  const int obase = wv * 32;                                                   \
  short8v wfrag[2][2];                                                         \
  _Pragma("unroll")                                                            \
  for (int ot = 0; ot < 2; ++ot)                                               \
    _Pragma("unroll")                                                          \
    for (int kt = 0; kt < 2; ++kt) {                                           \
      int o  = obase + ot * 16 + lr;                                           \
      int c0 = kt * 32 + lg * 8;                                               \
      float4 wa = *(const float4*)(pw + o * 64 + c0);                          \
      float4 wb = *(const float4*)(pw + o * 64 + c0 + 4);                      \
      short8v fr;                                                              \
      fr[0] = (short)f2bf(wa.x); fr[1] = (short)f2bf(wa.y);                    \
      fr[2] = (short)f2bf(wa.z); fr[3] = (short)f2bf(wa.w);                    \
      fr[4] = (short)f2bf(wb.x); fr[5] = (short)f2bf(wb.y);                    \
      fr[6] = (short)f2bf(wb.z); fr[7] = (short)f2bf(wb.w);                    \
      wfrag[ot][kt] = fr;                                                      \
    }

#define LDT(it, S) {                                                           \
  int p0 = (it) * 128;                                                         \
  _Pragma("unroll")                                                            \
  for (int i = 0; i < 4; ++i) {                                                \
    int f = tid + i * 256; int pos = f & 127; int c2q = f >> 7;                \
    const unsigned int* src = zb + (size_t)(c2q * 4) * THW + p0 + pos;         \
    S[i][0] = src[0];                                                          \
    S[i][1] = src[THW];                                                        \
    S[i][2] = src[2 * THW];                                                    \
    S[i][3] = src[3 * THW];                                                    \
  } }

#define STT(S, bf) {                                                           \
  _Pragma("unroll")                                                            \
  for (int i = 0; i < 4; ++i) {                                                \
    int f = tid + i * 256; int pos = f & 127; int c2q = f >> 7;                \
    *(uint4*)&zt[bf][pos * 36 + c2q * 4] =                                     \
        make_uint4(S[i][0], S[i][1], S[i][2], S[i][3]);                        \
  } }

#define MFMA_TILE(bufidx)                                                      \
  f32x4 acc[2][8];                                                             \
  _Pragma("unroll")                                                            \
  for (int ot = 0; ot < 2; ++ot)                                               \
    _Pragma("unroll")                                                          \
    for (int pt = 0; pt < 8; ++pt) {                                           \
      acc[ot][pt][0] = 0.f; acc[ot][pt][1] = 0.f;                              \
      acc[ot][pt][2] = 0.f; acc[ot][pt][3] = 0.f;                              \
    }                                                                          \
  {                                                                            \
    const unsigned int* ztb = &zt[bufidx][lr * 36 + lg * 4];                   \
    _Pragma("unroll")                                                          \
    for (int kt = 0; kt < 2; ++kt) {                                           \
      _Pragma("unroll")                                                        \
      for (int pt = 0; pt < 8; ++pt) {                                         \
        uint4 zr4 = *(const uint4*)(ztb + pt * (16 * 36) + kt * 16);           \
        union { uint4 u; short8v s; } zfu; zfu.u = zr4;                        \
        acc[0][pt] = __builtin_amdgcn_mfma_f32_16x16x32_bf16(                  \
            zfu.s, wfrag[0][kt], acc[0][pt], 0, 0, 0);                         \
        acc[1][pt] = __builtin_amdgcn_mfma_f32_16x16x32_bf16(                  \
            zfu.s, wfrag[1][kt], acc[1][pt], 0, 0, 0);                         \
      }                                                                        \
    }                                                                          \
  }

// bias-hoisted stats: raw sums only; pb folded in at the end.
#define STATS_BODY()                                                           \
  _Pragma("unroll")                                                            \
  for (int ot = 0; ot < 2; ++ot)                                               \
    _Pragma("unroll")                                                          \
    for (int pt = 0; pt < 8; ++pt)                                             \
      _Pragma("unroll")                                                        \
      for (int r = 0; r < 4; ++r) {                                            \
        float a = acc[ot][pt][r];                                              \
        s1p[ot] += a;                                                          \
        s2p[ot] = fmaf(a, a, s2p[ot]);                                         \
      }

// K2: GEMM over 4 subtiles -> per-(b,group) sum / sumsq (double atomics).
__global__ __launch_bounds__(256) void k2_stats(
    const unsigned int* __restrict__ zq, const float* __restrict__ pw,
    const float* __restrict__ pb, double* __restrict__ stats)
{
  __shared__ unsigned int zt[2][128 * 36];   // 36.9 KB
  const int tid = threadIdx.x;
  const int b  = blockIdx.x / 98;
  const int pg = blockIdx.x - b * 98;

  WFRAG_LOAD();
  const unsigned int* zb = zq + (size_t)(b * 32) * THW + pg * 512;

  unsigned int st[4][4];
  LDT(0, st); STT(st, 0);

  float s1p[2] = {0.f, 0.f}, s2p[2] = {0.f, 0.f};
  for (int it = 0; it < 4; ++it) {
    __syncthreads();
    if (it < 3) LDT(it + 1, st);
    MFMA_TILE(it & 1);
    if (it < 3) STT(st, (it + 1) & 1);
    STATS_BODY();
  }

  const float pb0 = pb[obase + lr], pb1 = pb[obase + 16 + lr];
  float s1 = (fmaf(128.f, pb0, s1p[0])) + (fmaf(128.f, pb1, s1p[1]));
  float s2 = (s2p[0] + fmaf(2.f * pb0, s1p[0], 128.f * pb0 * pb0))
           + (s2p[1] + fmaf(2.f * pb1, s1p[1], 128.f * pb1 * pb1));

#pragma unroll
  for (int off = 32; off; off >>= 1) {
    s1 += __shfl_xor(s1, off);
    s2 += __shfl_xor(s2, off);
  }
  if ((tid & 63) == 0) {
    atomicAdd(&stats[(b * 4 + wv) * 2 + 0], (double)s1);
    atomicAdd(&stats[(b * 4 + wv) * 2 + 1], (double)s2);
  }
}

#define STORE_BODY(itn)                                                        \
  _Pragma("unroll")                                                            \
  for (int ot = 0; ot < 2; ++ot) {                                             \
    int o = obase + ot * 16 + lr;                                              \
    float A = Ac[ot], B = Bc[ot];                                              \
    float* orow = ob + (size_t)o * THW + (itn) * 128;                          \
    _Pragma("unroll")                                                          \
    for (int pt = 0; pt < 8; ++pt) {                                           \
      f32x4 a = acc[ot][pt];                                                   \
      float4 v;                                                                \
      v.x = fmaf(a[0], A, B); v.x = v.x > 0.0f ? v.x : 0.0f;                   \
      v.y = fmaf(a[1], A, B); v.y = v.y > 0.0f ? v.y : 0.0f;                   \
      v.z = fmaf(a[2], A, B); v.z = v.z > 0.0f ? v.z : 0.0f;                   \
      v.w = fmaf(a[3], A, B); v.w = v.w > 0.0f ? v.w : 0.0f;                   \
      *(float4*)(orow + pt * 16) = v;                                          \
    }                                                                          \
  }

// K3: GEMM recompute over 4 subtiles -> GroupNorm + affine + ReLU -> out.
__global__ __launch_bounds__(256) void k3_norm(
    const unsigned int* __restrict__ zq, const float* __restrict__ pw,
    const float* __restrict__ pb, const double* __restrict__ stats,
    const float* __restrict__ gnw, const float* __restrict__ gnb,
    float* __restrict__ out)
{
  __shared__ unsigned int zt[2][128 * 36];
  const int tid = threadIdx.x;
  const int b  = blockIdx.x / 98;
  const int pg = blockIdx.x - b * 98;

  WFRAG_LOAD();

  double sm1 = stats[(b * 4 + wv) * 2 + 0];
  double sm2 = stats[(b * 4 + wv) * 2 + 1];
  double md = sm1 / NPG;
  double vd = sm2 / NPG - md * md;
  float m   = (float)md;
  float inv = rsqrtf((float)vd + 1e-5f);

  float Ac[2], Bc[2];
#pragma unroll
  for (int ot = 0; ot < 2; ++ot) {
    int o = obase + ot * 16 + lr;
    float A = inv * gnw[o];
    Ac[ot] = A;
    Bc[ot] = fmaf(pb[o] - m, A, gnb[o]);
  }

  const unsigned int* zb = zq + (size_t)(b * 32) * THW + pg * 512;
  float* ob = out + (size_t)(b * COUT) * THW + pg * 512 + lg * 4;

  unsigned int st[4][4];
  LDT(0, st); STT(st, 0);

  for (int it = 0; it < 4; ++it) {
    __syncthreads();
    if (it < 3) LDT(it + 1, st);
    MFMA_TILE(it & 1);
    if (it < 3) STT(st, (it + 1) & 1);
    STORE_BODY(it);
  }
}

// ---------------------------------------------------------------------------
extern "C" void kernel_launch(void* const* d_in, const int* in_sizes, int n_in,
                              void* d_out, int out_size, void* d_ws, size_t ws_size,
                              hipStream_t stream)
{
  const float* x   = (const float*)d_in[0];
  const float* sw  = (const float*)d_in[1];
  const float* sb  = (const float*)d_in[2];
  const float* tw  = (const float*)d_in[3];
  const float* tb  = (const float*)d_in[4];
  const float* pw  = (const float*)d_in[5];
  const float* pb  = (const float*)d_in[6];
  const float* gnw = (const float*)d_in[7];
  const float* gnb = (const float*)d_in[8];
  float* out = (float*)d_out;

  double* stats    = (double*)d_ws;                        // 64 doubles
  unsigned int* zq = (unsigned int*)((char*)d_ws + 512);   // bf16-pair z

  k1_dwconv<<<Bb * 32 * 2, 256, 0, stream>>>(x, sw, sb, tw, tb, zq, stats); // 512
  k2_stats<<<Bb * 98, 256, 0, stream>>>(zq, pw, pb, stats);
  k3_norm <<<Bb * 98, 256, 0, stream>>>(zq, pw, pb, stats, gnw, gnb, out);
}